// Round 19
// baseline (785.168 us; speedup 1.0000x reference)
//
#include <hip/hip_runtime.h>

#define NN 100000   // nodes
#define NE 1600000  // edges
#define CC 128      // channels
#define GG 50       // gaussians
#define EPB 128     // edges per block
#define NSCB 98     // scan blocks: ceil(100000/1024)

typedef _Float16 half8 __attribute__((ext_vector_type(8)));
typedef _Float16 half2v __attribute__((ext_vector_type(2)));
typedef float f32x4 __attribute__((ext_vector_type(4)));

static __device__ __forceinline__ f32x4 mfma16(half8 a, half8 b, f32x4 c) {
    return __builtin_amdgcn_mfma_f32_16x16x32_f16(a, b, c, 0, 0, 0);
}

// msg-row position p (0..127) <-> actual channel: p = hf*64 + lr*4 + q maps to
// channel lr*8 + hf*4 + q. Producer stores dense 128B runs; lin2 permutes its
// B-fragment K-index to compensate.
static __device__ __forceinline__ int perm_chan(int p) {
    return ((p >> 2) & 15) * 8 + (p >> 6) * 4 + (p & 3);
}

// ---------------------------------------------------------------------------
// Pack fn1 / fn2 weights into MFMA B-fragment order (f16) in ws.
// b1frag: [nb=8][ks=2][lane=64][8] at 0 — canonical channel nb*16+lr.
// b2frag: [nb=8][ks=4][lane=64][8] at +8192 — REMAPPED: tile nb, col lr ->
//   actual fn2 output channel lr*8+nb (lane owns contiguous lr*8..lr*8+7).
// ---------------------------------------------------------------------------
__global__ __launch_bounds__(256) void pack_frags(const float* fn1_w, const float* fn2_w,
                                                  _Float16* ws_frag)
{
    int tid = threadIdx.x;
    for (int s = tid; s < 1024; s += 256) {
        int l = s & 63, ks = (s >> 6) & 1, nb = s >> 7;
        int f = nb * 16 + (l & 15);
        int k0 = ks * 32 + 8 * (l >> 4);
        half8 v;
        #pragma unroll
        for (int i = 0; i < 8; i++) {
            int g = k0 + i;
            v[i] = (g < GG) ? (_Float16)fn1_w[f * GG + g] : (_Float16)0.f;
        }
        *reinterpret_cast<half8*>(&ws_frag[s * 8]) = v;
    }
    for (int s = tid; s < 2048; s += 256) {
        int l = s & 63, ks = (s >> 6) & 3, nb = s >> 8;
        int f = (l & 15) * 8 + nb;             // remapped output channel
        int k0 = ks * 32 + 8 * (l >> 4);
        const float* wp = fn2_w + f * CC + k0;
        half8 v;
        #pragma unroll
        for (int i = 0; i < 8; i++) v[i] = (_Float16)wp[i];
        *reinterpret_cast<half8*>(&ws_frag[8192 + s * 8]) = v;
    }
}

// ---------------------------------------------------------------------------
// out[r][f] = sum_k in[r][k]*w[f][k] + bias[f]  (f16 MFMA, f32 accum)
// DOH: fused histogram. PERMK: permute B staging K-index (msg-position order).
// ---------------------------------------------------------------------------
template <typename InT, typename OutT, bool DOH, bool PERMK>
__global__ __launch_bounds__(256) void lin_kernel(const InT* in, const float* w,
                                                  const float* bias, OutT* out, int nrows,
                                                  const int* hrow, int* hcnt)
{
    __shared__ __align__(16) _Float16 a_lds[64][136];
    __shared__ __align__(16) _Float16 bfrag[2048 * 8];

    int tid = threadIdx.x;
    int rowBase = blockIdx.x * 64;

    if constexpr (sizeof(InT) == 4) {
        for (int i = tid; i < 64 * 32; i += 256) {
            int r = i >> 5, c4 = i & 31;
            float4 v = {0.f, 0.f, 0.f, 0.f};
            if (rowBase + r < nrows)
                v = reinterpret_cast<const float4*>(in)[(size_t)(rowBase + r) * (CC / 4) + c4];
            a_lds[r][c4 * 4 + 0] = (_Float16)v.x;
            a_lds[r][c4 * 4 + 1] = (_Float16)v.y;
            a_lds[r][c4 * 4 + 2] = (_Float16)v.z;
            a_lds[r][c4 * 4 + 3] = (_Float16)v.w;
        }
    } else {
        for (int i = tid; i < 64 * 16; i += 256) {
            int r = i >> 4, c8 = i & 15;
            half8 v;
            #pragma unroll
            for (int k = 0; k < 8; k++) v[k] = (_Float16)0.f;
            if (rowBase + r < nrows)
                v = reinterpret_cast<const half8*>(in)[(size_t)(rowBase + r) * (CC / 8) + c8];
            *reinterpret_cast<half8*>(&a_lds[r][c8 * 8]) = v;
        }
    }
    for (int s = tid; s < 2048; s += 256) {
        int l = s & 63, ks = (s >> 6) & 3, nb = s >> 8;
        int f = nb * 16 + (l & 15);
        int k0 = ks * 32 + 8 * (l >> 4);
        const float* wrow = w + f * CC;
        half8 v;
        #pragma unroll
        for (int i = 0; i < 8; i++) {
            int k = k0 + i;
            int rk = PERMK ? perm_chan(k) : k;
            v[i] = (_Float16)wrow[rk];
        }
        *reinterpret_cast<half8*>(&bfrag[s * 8]) = v;
    }

    if constexpr (DOH) {
        int idx4 = blockIdx.x * 256 + tid;
        if (idx4 < NE / 4) {
            int4 e4 = reinterpret_cast<const int4*>(hrow)[idx4];
            atomicAdd(&hcnt[e4.x], 1);
            atomicAdd(&hcnt[e4.y], 1);
            atomicAdd(&hcnt[e4.z], 1);
            atomicAdd(&hcnt[e4.w], 1);
        }
    }
    __syncthreads();

    int wid = tid >> 6, l = tid & 63;
    int lr = l & 15, lg = l >> 4;
    int wrow = wid * 16;

    half8 afr[4];
    #pragma unroll
    for (int ks = 0; ks < 4; ks++)
        afr[ks] = *reinterpret_cast<const half8*>(&a_lds[wrow + lr][ks * 32 + 8 * lg]);

    #pragma unroll
    for (int nb = 0; nb < 8; nb++) {
        f32x4 acc = {0.f, 0.f, 0.f, 0.f};
        #pragma unroll
        for (int ks = 0; ks < 4; ks++) {
            half8 bf = *reinterpret_cast<const half8*>(&bfrag[((nb * 4 + ks) * 64 + l) * 8]);
            acc = mfma16(afr[ks], bf, acc);
        }
        float bv = bias[nb * 16 + lr];
        #pragma unroll
        for (int j = 0; j < 4; j++) {
            int r = rowBase + wrow + lg * 4 + j;
            if (r < nrows) out[(size_t)r * CC + nb * 16 + lr] = (OutT)(acc[j] + bv);
        }
    }
}

// ------------------------------ scans (CSR) ---------------------------------
__global__ __launch_bounds__(256) void scanA(const int* cnt, int* excl, int* bsum, int n) {
    __shared__ int lds[256];
    int b = blockIdx.x, t = threadIdx.x;
    int base = b * 1024 + t * 4;
    int v[4];
    #pragma unroll
    for (int i = 0; i < 4; i++) v[i] = (base + i < n) ? cnt[base + i] : 0;
    int s = v[0] + v[1] + v[2] + v[3];
    lds[t] = s;
    __syncthreads();
    for (int off = 1; off < 256; off <<= 1) {
        int x = (t >= off) ? lds[t - off] : 0;
        __syncthreads();
        lds[t] += x;
        __syncthreads();
    }
    int incl = lds[t];
    int run = incl - s;
    #pragma unroll
    for (int i = 0; i < 4; i++) {
        if (base + i < n) excl[base + i] = run;
        run += v[i];
    }
    if (t == 255) bsum[b] = incl;
}

__global__ __launch_bounds__(128) void scanB(int* bsum, int n) {
    __shared__ int lds[128];
    int t = threadIdx.x;
    int v = (t < n) ? bsum[t] : 0;
    lds[t] = v;
    __syncthreads();
    for (int off = 1; off < 128; off <<= 1) {
        int x = (t >= off) ? lds[t - off] : 0;
        __syncthreads();
        lds[t] += x;
        __syncthreads();
    }
    if (t < n) bsum[t] = lds[t] - v;  // exclusive
}

__global__ __launch_bounds__(256) void scanC(int* excl, const int* bsum, int* cursor, int n) {
    int b = blockIdx.x, t = threadIdx.x;
    int off = bsum[b];
    int base = b * 1024 + t * 4;
    #pragma unroll
    for (int i = 0; i < 4; i++) {
        int idx = base + i;
        if (idx < n) {
            int val = excl[idx] + off;
            excl[idx] = val;
            cursor[idx] = val;
        }
    }
}

// ---------------------------------------------------------------------------
// Kernel A: natural-order edges; compute msg, claim sorted slot (int atomic,
// hidden under MFMA), store msg rows in permuted dense layout. x1 gathered as
// 4x uint4 (full 16B/lane — dense wave footprint) at the TOP of stage 2, so
// the 4 independent loads overlap the 32-MFMA cluster (MLP within the stage,
// no cross-barrier live range).
// ---------------------------------------------------------------------------
__global__ __launch_bounds__(512, 8) void msg_scatter_kernel(
    const _Float16* __restrict__ x1, const int* __restrict__ eidx,
    const float* __restrict__ ea, const _Float16* __restrict__ frag_ws,
    const float* __restrict__ fn1_b, const float* __restrict__ fn2_b,
    int* __restrict__ cursor, _Float16* __restrict__ msg)
{
    __shared__ __align__(16) unsigned char u_lds[EPB * CC * 2];  // 32 KB
    __shared__ int cols_l[EPB];
    __shared__ int p_l[EPB];

    int tid = threadIdx.x;
    size_t eBase = (size_t)blockIdx.x * EPB;

    if (tid < EPB) {
        int r = eidx[eBase + tid];
        cols_l[tid] = eidx[(size_t)NE + eBase + tid];
        p_l[tid] = atomicAdd(&cursor[r], 1);   // slot claim, latency hidden
    }
    // edge_attr tile -> f16 LDS, swizzled rows of 64 (g 50..63 zero-padded)
    {
        const float2* eap = reinterpret_cast<const float2*>(ea + eBase * GG);
        for (int i = tid; i < EPB * 25; i += 512) {
            int e = i / 25, g2 = i - e * 25;
            float2 v = eap[i];
            int byte = e * 128 + ((g2 * 4) ^ ((e & 7) << 4));
            _Float16* p = reinterpret_cast<_Float16*>(u_lds + byte);
            p[0] = (_Float16)v.x;
            p[1] = (_Float16)v.y;
        }
        for (int i = tid; i < EPB * 14; i += 512) {
            int e = i / 14, g = (i - e * 14) + 50;
            int byte = e * 128 + ((g * 2) ^ ((e & 7) << 4));
            *reinterpret_cast<_Float16*>(u_lds + byte) = (_Float16)0.f;
        }
    }
    __syncthreads();

    int wv = tid >> 6, l = tid & 63;
    int lr = l & 15, lg = l >> 4;
    int erow = wv * 16;

    // stage-1 A fragments
    half8 a1[2];
    #pragma unroll
    for (int ks = 0; ks < 2; ks++) {
        int e = erow + lr;
        int byte = e * 128 + ((ks * 64 + lg * 16) ^ ((e & 7) << 4));
        a1[ks] = *reinterpret_cast<const half8*>(u_lds + byte);
    }
    __syncthreads();  // all ea reads complete before h overwrites u_lds

    // ---- stage 1: h = shifted_softplus(ea @ fn1^T + b1) -> u_lds [128][256B]
    #pragma unroll
    for (int nb = 0; nb < 8; nb++) {
        half8 b10 = *reinterpret_cast<const half8*>(&frag_ws[((nb * 2 + 0) * 64 + l) * 8]);
        half8 b11 = *reinterpret_cast<const half8*>(&frag_ws[((nb * 2 + 1) * 64 + l) * 8]);
        f32x4 acc = {0.f, 0.f, 0.f, 0.f};
        acc = mfma16(a1[0], b10, acc);
        acc = mfma16(a1[1], b11, acc);
        float bv = fn1_b[nb * 16 + lr];
        int f = nb * 16 + lr;
        #pragma unroll
        for (int j = 0; j < 4; j++) {
            float z = acc[j] + bv;
            float t = __expf(-fabsf(z));
            float hz = fmaxf(z, 0.f) + __logf(1.f + t) - 0.69314718055994531f;
            int e = erow + lg * 4 + j;
            int byte = e * 256 + ((f * 2) ^ ((e & 7) << 4));
            *reinterpret_cast<_Float16*>(u_lds + byte) = (_Float16)hz;
        }
    }
    __syncthreads();

    // ---- stage 2 (remapped): W cols = channels lr*8..lr*8+7 ----
    half8 a2[4];
    #pragma unroll
    for (int ks = 0; ks < 4; ks++) {
        int e = erow + lr;
        int byte = e * 256 + ((ks * 64 + lg * 16) ^ ((e & 7) << 4));
        a2[ks] = *reinterpret_cast<const half8*>(u_lds + byte);
    }
    int pp[4], cc4[4];
    #pragma unroll
    for (int j = 0; j < 4; j++) {
        int e = erow + lg * 4 + j;
        pp[j] = p_l[e];
        cc4[j] = cols_l[e];
    }
    // x1 gather: 4 independent 16B loads (dense wave footprint: 16 lanes cover
    // a full 256B row per instruction); latency hides under the MFMA cluster.
    uint4 xq[4];
    #pragma unroll
    for (int j = 0; j < 4; j++)
        xq[j] = *reinterpret_cast<const uint4*>(&x1[(size_t)cc4[j] * CC + lr * 8]);

    const half8* b2g = reinterpret_cast<const half8*>(frag_ws + 8192);
    #pragma unroll
    for (int hf = 0; hf < 2; hf++) {
        f32x4 acc[4];
        #pragma unroll
        for (int q = 0; q < 4; q++) {
            int nb = hf * 4 + q;
            f32x4 a = {0.f, 0.f, 0.f, 0.f};
            #pragma unroll
            for (int ks = 0; ks < 4; ks++)
                a = mfma16(a2[ks], b2g[(nb * 4 + ks) * 64 + l], a);
            acc[q] = a;
        }
        int ch0 = lr * 8 + hf * 4;             // canonical channels (x1 side)
        int pos0 = hf * 64 + lr * 4;           // permuted msg position
        float4 bv = *reinterpret_cast<const float4*>(&fn2_b[ch0]);

        #pragma unroll
        for (int j = 0; j < 4; j++) {
            unsigned w0 = (hf == 0) ? xq[j].x : xq[j].z;
            unsigned w1 = (hf == 0) ? xq[j].y : xq[j].w;
            half2v x01 = __builtin_bit_cast(half2v, w0);
            half2v x23 = __builtin_bit_cast(half2v, w1);
            half2v p0, p1;
            p0[0] = (_Float16)((float)x01[0] * (acc[0][j] + bv.x));
            p0[1] = (_Float16)((float)x01[1] * (acc[1][j] + bv.y));
            p1[0] = (_Float16)((float)x23[0] * (acc[2][j] + bv.z));
            p1[1] = (_Float16)((float)x23[1] * (acc[3][j] + bv.w));
            uint2 st;
            st.x = __builtin_bit_cast(unsigned, p0);
            st.y = __builtin_bit_cast(unsigned, p1);
            *reinterpret_cast<uint2*>(&msg[(size_t)pp[j] * CC + pos0]) = st;
        }
    }
}

// ---------------------------------------------------------------------------
// Kernel B: CSR reduce (position-wise, layout-agnostic). Wave per node; msg
// rows for a node are CONSECUTIVE -> linear streaming. f32 accum, zero atomics.
// ---------------------------------------------------------------------------
__global__ __launch_bounds__(512, 8) void gather_reduce_kernel(
    const _Float16* __restrict__ msg, const int* __restrict__ rowptr,
    _Float16* __restrict__ aggH)
{
    int tid = threadIdx.x;
    int r = blockIdx.x * 8 + (tid >> 6);
    int l = tid & 63;
    int e0 = rowptr[r];
    int e1 = (r == NN - 1) ? NE : rowptr[r + 1];

    const unsigned* base = reinterpret_cast<const unsigned*>(msg) + l;
    float a0 = 0.f, a1 = 0.f;
    int i = e0;
    for (; i + 1 < e1; i += 2) {
        unsigned v0 = base[(size_t)i * 64];
        unsigned v1 = base[(size_t)(i + 1) * 64];
        half2v h0 = __builtin_bit_cast(half2v, v0);
        half2v h1 = __builtin_bit_cast(half2v, v1);
        a0 += (float)h0[0] + (float)h1[0];
        a1 += (float)h0[1] + (float)h1[1];
    }
    if (i < e1) {
        half2v h = __builtin_bit_cast(half2v, base[(size_t)i * 64]);
        a0 += (float)h[0];
        a1 += (float)h[1];
    }
    half2v o;
    o[0] = (_Float16)a0;
    o[1] = (_Float16)a1;
    reinterpret_cast<unsigned*>(aggH)[(size_t)r * 64 + l] = __builtin_bit_cast(unsigned, o);
}

// ---------------- fallback atomic edge kernel (remapped stage 2) ------------
__global__ __launch_bounds__(512, 8) void edge_kernel_atomic(
    const _Float16* __restrict__ x1, const int* __restrict__ eidx,
    const float* __restrict__ ea, const _Float16* __restrict__ frag_ws,
    const float* __restrict__ fn1_b, const float* __restrict__ fn2_b,
    float* __restrict__ agg)
{
    __shared__ __align__(16) unsigned char u_lds[EPB * CC * 2];
    __shared__ int rows_l[EPB];
    __shared__ int cols_l[EPB];

    int tid = threadIdx.x;
    size_t eBase = (size_t)blockIdx.x * EPB;

    if (tid < EPB) {
        rows_l[tid] = eidx[eBase + tid];
        cols_l[tid] = eidx[(size_t)NE + eBase + tid];
    }
    {
        const float2* eap = reinterpret_cast<const float2*>(ea + eBase * GG);
        for (int i = tid; i < EPB * 25; i += 512) {
            int e = i / 25, g2 = i - e * 25;
            float2 v = eap[i];
            int byte = e * 128 + ((g2 * 4) ^ ((e & 7) << 4));
            _Float16* p = reinterpret_cast<_Float16*>(u_lds + byte);
            p[0] = (_Float16)v.x;
            p[1] = (_Float16)v.y;
        }
        for (int i = tid; i < EPB * 14; i += 512) {
            int e = i / 14, g = (i - e * 14) + 50;
            int byte = e * 128 + ((g * 2) ^ ((e & 7) << 4));
            *reinterpret_cast<_Float16*>(u_lds + byte) = (_Float16)0.f;
        }
    }
    __syncthreads();

    int wv = tid >> 6, l = tid & 63;
    int lr = l & 15, lg = l >> 4;
    int erow = wv * 16;

    half8 a1[2];
    #pragma unroll
    for (int ks = 0; ks < 2; ks++) {
        int e = erow + lr;
        int byte = e * 128 + ((ks * 64 + lg * 16) ^ ((e & 7) << 4));
        a1[ks] = *reinterpret_cast<const half8*>(u_lds + byte);
    }
    __syncthreads();

    #pragma unroll
    for (int nb = 0; nb < 8; nb++) {
        half8 b10 = *reinterpret_cast<const half8*>(&frag_ws[((nb * 2 + 0) * 64 + l) * 8]);
        half8 b11 = *reinterpret_cast<const half8*>(&frag_ws[((nb * 2 + 1) * 64 + l) * 8]);
        f32x4 acc = {0.f, 0.f, 0.f, 0.f};
        acc = mfma16(a1[0], b10, acc);
        acc = mfma16(a1[1], b11, acc);
        float bv = fn1_b[nb * 16 + lr];
        int f = nb * 16 + lr;
        #pragma unroll
        for (int j = 0; j < 4; j++) {
            float z = acc[j] + bv;
            float t = __expf(-fabsf(z));
            float hz = fmaxf(z, 0.f) + __logf(1.f + t) - 0.69314718055994531f;
            int e = erow + lg * 4 + j;
            int byte = e * 256 + ((f * 2) ^ ((e & 7) << 4));
            *reinterpret_cast<_Float16*>(u_lds + byte) = (_Float16)hz;
        }
    }
    __syncthreads();

    half8 a2[4];
    #pragma unroll
    for (int ks = 0; ks < 4; ks++) {
        int e = erow + lr;
        int byte = e * 256 + ((ks * 64 + lg * 16) ^ ((e & 7) << 4));
        a2[ks] = *reinterpret_cast<const half8*>(u_lds + byte);
    }
    int rr[4], cc4[4];
    #pragma unroll
    for (int j = 0; j < 4; j++) {
        int e = erow + lg * 4 + j;
        rr[j] = rows_l[e];
        cc4[j] = cols_l[e];
    }
    const half8* b2g = reinterpret_cast<const half8*>(frag_ws + 8192);
    #pragma unroll
    for (int hf = 0; hf < 2; hf++) {
        f32x4 acc[4];
        #pragma unroll
        for (int q = 0; q < 4; q++) {
            int nb = hf * 4 + q;
            f32x4 a = {0.f, 0.f, 0.f, 0.f};
            #pragma unroll
            for (int ks = 0; ks < 4; ks++)
                a = mfma16(a2[ks], b2g[(nb * 4 + ks) * 64 + l], a);
            acc[q] = a;
        }
        int ch0 = lr * 8 + hf * 4;
        float4 bv = *reinterpret_cast<const float4*>(&fn2_b[ch0]);
        #pragma unroll
        for (int j = 0; j < 4; j++) {
            uint2 xp = *reinterpret_cast<const uint2*>(&x1[(size_t)cc4[j] * CC + ch0]);
            half2v x01 = __builtin_bit_cast(half2v, xp.x);
            half2v x23 = __builtin_bit_cast(half2v, xp.y);
            float* dst = &agg[(size_t)rr[j] * CC + ch0];
            atomicAdd(dst + 0, (float)x01[0] * (acc[0][j] + bv.x));
            atomicAdd(dst + 1, (float)x01[1] * (acc[1][j] + bv.y));
            atomicAdd(dst + 2, (float)x23[0] * (acc[2][j] + bv.z));
            atomicAdd(dst + 3, (float)x23[1] * (acc[3][j] + bv.w));
        }
    }
}

extern "C" void kernel_launch(void* const* d_in, const int* in_sizes, int n_in,
                              void* d_out, int out_size, void* d_ws, size_t ws_size,
                              hipStream_t stream) {
    const float* x      = (const float*)d_in[0];
    const int*   eidx   = (const int*)d_in[1];
    const float* ea     = (const float*)d_in[2];
    const float* lin1_w = (const float*)d_in[3];
    const float* lin1_b = (const float*)d_in[4];
    const float* lin2_w = (const float*)d_in[5];
    const float* lin2_b = (const float*)d_in[6];
    const float* fn1_w  = (const float*)d_in[7];
    const float* fn1_b  = (const float*)d_in[8];
    const float* fn2_w  = (const float*)d_in[9];
    const float* fn2_b  = (const float*)d_in[10];

    float* out = (float*)d_out;

    // ws layout (bytes)
    const size_t o_frag = 0;                                   // 48 KB used
    const size_t o_x1h  = 65536;                               // 25.6 MB
    const size_t o_msg  = o_x1h + (size_t)NN * CC * 2;         // 409.6 MB
    const size_t o_aggH = o_msg + (size_t)NE * CC * 2;         // 25.6 MB
    const size_t o_cnt  = o_aggH + (size_t)NN * CC * 2;        // 400 KB
    const size_t o_rp   = o_cnt + (size_t)NN * 4;              // 400 KB
    const size_t o_cur  = o_rp + (size_t)NN * 4;               // 400 KB
    const size_t o_bsum = o_cur + (size_t)NN * 4;              // 512 B
    const size_t req    = o_bsum + 512;

    _Float16* frag_ws = (_Float16*)((char*)d_ws + o_frag);
    _Float16* x1h     = (_Float16*)((char*)d_ws + o_x1h);

    pack_frags<<<1, 256, 0, stream>>>(fn1_w, fn2_w, frag_ws);

    if (ws_size >= req) {
        _Float16* msg  = (_Float16*)((char*)d_ws + o_msg);
        _Float16* aggH = (_Float16*)((char*)d_ws + o_aggH);
        int* cnt    = (int*)((char*)d_ws + o_cnt);
        int* rowptr = (int*)((char*)d_ws + o_rp);
        int* cursor = (int*)((char*)d_ws + o_cur);
        int* bsum   = (int*)((char*)d_ws + o_bsum);

        hipMemsetAsync(cnt, 0, (size_t)NN * 4, stream);
        // lin1 + fused histogram (atomics hide under MFMA)
        lin_kernel<float, _Float16, true, false><<<(NN + 63) / 64, 256, 0, stream>>>(
            x, lin1_w, lin1_b, x1h, NN, eidx, cnt);
        scanA<<<NSCB, 256, 0, stream>>>(cnt, rowptr, bsum, NN);
        scanB<<<1, 128, 0, stream>>>(bsum, NSCB);
        scanC<<<NSCB, 256, 0, stream>>>(rowptr, bsum, cursor, NN);

        msg_scatter_kernel<<<NE / EPB, 512, 0, stream>>>(x1h, eidx, ea, frag_ws,
                                                         fn1_b, fn2_b, cursor, msg);
        gather_reduce_kernel<<<NN / 8, 512, 0, stream>>>(msg, rowptr, aggH);
        // lin2 with permuted K to match msg/agg position layout
        lin_kernel<_Float16, float, false, true><<<(NN + 63) / 64, 256, 0, stream>>>(
            aggH, lin2_w, lin2_b, out, NN, nullptr, nullptr);
    } else {
        lin_kernel<float, _Float16, false, false><<<(NN + 63) / 64, 256, 0, stream>>>(
            x, lin1_w, lin1_b, x1h, NN, nullptr, nullptr);
        hipMemsetAsync(out, 0, (size_t)NN * CC * sizeof(float), stream);
        edge_kernel_atomic<<<NE / EPB, 512, 0, stream>>>(x1h, eidx, ea, frag_ws,
                                                         fn1_b, fn2_b, out);
        lin_kernel<float, float, false, false><<<(NN + 63) / 64, 256, 0, stream>>>(
            out, lin2_w, lin2_b, out, NN, nullptr, nullptr);
    }
}

// Round 20
// 662.589 us; speedup vs baseline: 1.1850x; 1.1850x over previous
//
#include <hip/hip_runtime.h>

#define NN 100000   // nodes
#define NE 1600000  // edges
#define CC 128      // channels
#define GG 50       // gaussians
#define EPB 128     // edges per block
#define NSCB 98     // scan blocks: ceil(100000/1024)

typedef _Float16 half8 __attribute__((ext_vector_type(8)));
typedef _Float16 half2v __attribute__((ext_vector_type(2)));
typedef float f32x4 __attribute__((ext_vector_type(4)));

static __device__ __forceinline__ f32x4 mfma16(half8 a, half8 b, f32x4 c) {
    return __builtin_amdgcn_mfma_f32_16x16x32_f16(a, b, c, 0, 0, 0);
}

// msg-row position p (0..127) <-> actual channel: p = hf*64 + lr*4 + q maps to
// channel lr*8 + hf*4 + q. Producer stores dense 128B runs; lin2 permutes its
// B-fragment K-index to compensate.
static __device__ __forceinline__ int perm_chan(int p) {
    return ((p >> 2) & 15) * 8 + (p >> 6) * 4 + (p & 3);
}

// ---------------------------------------------------------------------------
// Pack fn1 / fn2 weights into MFMA B-fragment order (f16) in ws.
// b1frag: [nb=8][ks=2][lane=64][8] at 0 — canonical channel nb*16+lr.
// b2frag: [nb=8][ks=4][lane=64][8] at +8192 — REMAPPED: tile nb, col lr ->
//   actual fn2 output channel lr*8+nb (lane owns contiguous lr*8..lr*8+7).
// ---------------------------------------------------------------------------
__global__ __launch_bounds__(256) void pack_frags(const float* fn1_w, const float* fn2_w,
                                                  _Float16* ws_frag)
{
    int tid = threadIdx.x;
    for (int s = tid; s < 1024; s += 256) {
        int l = s & 63, ks = (s >> 6) & 1, nb = s >> 7;
        int f = nb * 16 + (l & 15);
        int k0 = ks * 32 + 8 * (l >> 4);
        half8 v;
        #pragma unroll
        for (int i = 0; i < 8; i++) {
            int g = k0 + i;
            v[i] = (g < GG) ? (_Float16)fn1_w[f * GG + g] : (_Float16)0.f;
        }
        *reinterpret_cast<half8*>(&ws_frag[s * 8]) = v;
    }
    for (int s = tid; s < 2048; s += 256) {
        int l = s & 63, ks = (s >> 6) & 3, nb = s >> 8;
        int f = (l & 15) * 8 + nb;             // remapped output channel
        int k0 = ks * 32 + 8 * (l >> 4);
        const float* wp = fn2_w + f * CC + k0;
        half8 v;
        #pragma unroll
        for (int i = 0; i < 8; i++) v[i] = (_Float16)wp[i];
        *reinterpret_cast<half8*>(&ws_frag[8192 + s * 8]) = v;
    }
}

// ---------------------------------------------------------------------------
// out[r][f] = sum_k in[r][k]*w[f][k] + bias[f]  (f16 MFMA, f32 accum)
// DOH: fused histogram. PERMK: permute B staging K-index (msg-position order).
// ---------------------------------------------------------------------------
template <typename InT, typename OutT, bool DOH, bool PERMK>
__global__ __launch_bounds__(256) void lin_kernel(const InT* in, const float* w,
                                                  const float* bias, OutT* out, int nrows,
                                                  const int* hrow, int* hcnt)
{
    __shared__ __align__(16) _Float16 a_lds[64][136];
    __shared__ __align__(16) _Float16 bfrag[2048 * 8];

    int tid = threadIdx.x;
    int rowBase = blockIdx.x * 64;

    if constexpr (sizeof(InT) == 4) {
        for (int i = tid; i < 64 * 32; i += 256) {
            int r = i >> 5, c4 = i & 31;
            float4 v = {0.f, 0.f, 0.f, 0.f};
            if (rowBase + r < nrows)
                v = reinterpret_cast<const float4*>(in)[(size_t)(rowBase + r) * (CC / 4) + c4];
            a_lds[r][c4 * 4 + 0] = (_Float16)v.x;
            a_lds[r][c4 * 4 + 1] = (_Float16)v.y;
            a_lds[r][c4 * 4 + 2] = (_Float16)v.z;
            a_lds[r][c4 * 4 + 3] = (_Float16)v.w;
        }
    } else {
        for (int i = tid; i < 64 * 16; i += 256) {
            int r = i >> 4, c8 = i & 15;
            half8 v;
            #pragma unroll
            for (int k = 0; k < 8; k++) v[k] = (_Float16)0.f;
            if (rowBase + r < nrows)
                v = reinterpret_cast<const half8*>(in)[(size_t)(rowBase + r) * (CC / 8) + c8];
            *reinterpret_cast<half8*>(&a_lds[r][c8 * 8]) = v;
        }
    }
    for (int s = tid; s < 2048; s += 256) {
        int l = s & 63, ks = (s >> 6) & 3, nb = s >> 8;
        int f = nb * 16 + (l & 15);
        int k0 = ks * 32 + 8 * (l >> 4);
        const float* wrow = w + f * CC;
        half8 v;
        #pragma unroll
        for (int i = 0; i < 8; i++) {
            int k = k0 + i;
            int rk = PERMK ? perm_chan(k) : k;
            v[i] = (_Float16)wrow[rk];
        }
        *reinterpret_cast<half8*>(&bfrag[s * 8]) = v;
    }

    if constexpr (DOH) {
        int idx4 = blockIdx.x * 256 + tid;
        if (idx4 < NE / 4) {
            int4 e4 = reinterpret_cast<const int4*>(hrow)[idx4];
            atomicAdd(&hcnt[e4.x], 1);
            atomicAdd(&hcnt[e4.y], 1);
            atomicAdd(&hcnt[e4.z], 1);
            atomicAdd(&hcnt[e4.w], 1);
        }
    }
    __syncthreads();

    int wid = tid >> 6, l = tid & 63;
    int lr = l & 15, lg = l >> 4;
    int wrow = wid * 16;

    half8 afr[4];
    #pragma unroll
    for (int ks = 0; ks < 4; ks++)
        afr[ks] = *reinterpret_cast<const half8*>(&a_lds[wrow + lr][ks * 32 + 8 * lg]);

    #pragma unroll
    for (int nb = 0; nb < 8; nb++) {
        f32x4 acc = {0.f, 0.f, 0.f, 0.f};
        #pragma unroll
        for (int ks = 0; ks < 4; ks++) {
            half8 bf = *reinterpret_cast<const half8*>(&bfrag[((nb * 4 + ks) * 64 + l) * 8]);
            acc = mfma16(afr[ks], bf, acc);
        }
        float bv = bias[nb * 16 + lr];
        #pragma unroll
        for (int j = 0; j < 4; j++) {
            int r = rowBase + wrow + lg * 4 + j;
            if (r < nrows) out[(size_t)r * CC + nb * 16 + lr] = (OutT)(acc[j] + bv);
        }
    }
}

// ------------------------------ scans (CSR) ---------------------------------
__global__ __launch_bounds__(256) void scanA(const int* cnt, int* excl, int* bsum, int n) {
    __shared__ int lds[256];
    int b = blockIdx.x, t = threadIdx.x;
    int base = b * 1024 + t * 4;
    int v[4];
    #pragma unroll
    for (int i = 0; i < 4; i++) v[i] = (base + i < n) ? cnt[base + i] : 0;
    int s = v[0] + v[1] + v[2] + v[3];
    lds[t] = s;
    __syncthreads();
    for (int off = 1; off < 256; off <<= 1) {
        int x = (t >= off) ? lds[t - off] : 0;
        __syncthreads();
        lds[t] += x;
        __syncthreads();
    }
    int incl = lds[t];
    int run = incl - s;
    #pragma unroll
    for (int i = 0; i < 4; i++) {
        if (base + i < n) excl[base + i] = run;
        run += v[i];
    }
    if (t == 255) bsum[b] = incl;
}

__global__ __launch_bounds__(128) void scanB(int* bsum, int n) {
    __shared__ int lds[128];
    int t = threadIdx.x;
    int v = (t < n) ? bsum[t] : 0;
    lds[t] = v;
    __syncthreads();
    for (int off = 1; off < 128; off <<= 1) {
        int x = (t >= off) ? lds[t - off] : 0;
        __syncthreads();
        lds[t] += x;
        __syncthreads();
    }
    if (t < n) bsum[t] = lds[t] - v;  // exclusive
}

__global__ __launch_bounds__(256) void scanC(int* excl, const int* bsum, int* cursor, int n) {
    int b = blockIdx.x, t = threadIdx.x;
    int off = bsum[b];
    int base = b * 1024 + t * 4;
    #pragma unroll
    for (int i = 0; i < 4; i++) {
        int idx = base + i;
        if (idx < n) {
            int val = excl[idx] + off;
            excl[idx] = val;
            cursor[idx] = val;
        }
    }
}

// ---------------------------------------------------------------------------
// Kernel A: natural-order edges; compute msg, claim sorted slot (int atomic,
// hidden under MFMA), store msg rows from registers in PERMUTED layout:
// per (hf,j) instruction, 16 lanes write contiguous 128B — full density,
// each 64B sector written exactly once. x1 loads at consumption (every
// extended-live-range variant spilled: r11/r16/r19).
// ---------------------------------------------------------------------------
__global__ __launch_bounds__(512, 8) void msg_scatter_kernel(
    const _Float16* __restrict__ x1, const int* __restrict__ eidx,
    const float* __restrict__ ea, const _Float16* __restrict__ frag_ws,
    const float* __restrict__ fn1_b, const float* __restrict__ fn2_b,
    int* __restrict__ cursor, _Float16* __restrict__ msg)
{
    __shared__ __align__(16) unsigned char u_lds[EPB * CC * 2];  // 32 KB
    __shared__ int cols_l[EPB];
    __shared__ int p_l[EPB];

    int tid = threadIdx.x;
    size_t eBase = (size_t)blockIdx.x * EPB;

    if (tid < EPB) {
        int r = eidx[eBase + tid];
        cols_l[tid] = eidx[(size_t)NE + eBase + tid];
        p_l[tid] = atomicAdd(&cursor[r], 1);   // slot claim, latency hidden
    }
    // edge_attr tile -> f16 LDS, swizzled rows of 64 (g 50..63 zero-padded)
    {
        const float2* eap = reinterpret_cast<const float2*>(ea + eBase * GG);
        for (int i = tid; i < EPB * 25; i += 512) {
            int e = i / 25, g2 = i - e * 25;
            float2 v = eap[i];
            int byte = e * 128 + ((g2 * 4) ^ ((e & 7) << 4));
            _Float16* p = reinterpret_cast<_Float16*>(u_lds + byte);
            p[0] = (_Float16)v.x;
            p[1] = (_Float16)v.y;
        }
        for (int i = tid; i < EPB * 14; i += 512) {
            int e = i / 14, g = (i - e * 14) + 50;
            int byte = e * 128 + ((g * 2) ^ ((e & 7) << 4));
            *reinterpret_cast<_Float16*>(u_lds + byte) = (_Float16)0.f;
        }
    }
    __syncthreads();

    int wv = tid >> 6, l = tid & 63;
    int lr = l & 15, lg = l >> 4;
    int erow = wv * 16;

    // stage-1 A fragments
    half8 a1[2];
    #pragma unroll
    for (int ks = 0; ks < 2; ks++) {
        int e = erow + lr;
        int byte = e * 128 + ((ks * 64 + lg * 16) ^ ((e & 7) << 4));
        a1[ks] = *reinterpret_cast<const half8*>(u_lds + byte);
    }
    __syncthreads();  // all ea reads complete before h overwrites u_lds

    // ---- stage 1: h = shifted_softplus(ea @ fn1^T + b1) -> u_lds [128][256B]
    #pragma unroll
    for (int nb = 0; nb < 8; nb++) {
        half8 b10 = *reinterpret_cast<const half8*>(&frag_ws[((nb * 2 + 0) * 64 + l) * 8]);
        half8 b11 = *reinterpret_cast<const half8*>(&frag_ws[((nb * 2 + 1) * 64 + l) * 8]);
        f32x4 acc = {0.f, 0.f, 0.f, 0.f};
        acc = mfma16(a1[0], b10, acc);
        acc = mfma16(a1[1], b11, acc);
        float bv = fn1_b[nb * 16 + lr];
        int f = nb * 16 + lr;
        #pragma unroll
        for (int j = 0; j < 4; j++) {
            float z = acc[j] + bv;
            float t = __expf(-fabsf(z));
            float hz = fmaxf(z, 0.f) + __logf(1.f + t) - 0.69314718055994531f;
            int e = erow + lg * 4 + j;
            int byte = e * 256 + ((f * 2) ^ ((e & 7) << 4));
            *reinterpret_cast<_Float16*>(u_lds + byte) = (_Float16)hz;
        }
    }
    __syncthreads();

    // ---- stage 2 (remapped): W cols = channels lr*8..lr*8+7 ----
    half8 a2[4];
    #pragma unroll
    for (int ks = 0; ks < 4; ks++) {
        int e = erow + lr;
        int byte = e * 256 + ((ks * 64 + lg * 16) ^ ((e & 7) << 4));
        a2[ks] = *reinterpret_cast<const half8*>(u_lds + byte);
    }
    int pp[4], cc4[4];
    #pragma unroll
    for (int j = 0; j < 4; j++) {
        int e = erow + lg * 4 + j;
        pp[j] = p_l[e];
        cc4[j] = cols_l[e];
    }

    const half8* b2g = reinterpret_cast<const half8*>(frag_ws + 8192);
    #pragma unroll
    for (int hf = 0; hf < 2; hf++) {
        f32x4 acc[4];
        #pragma unroll
        for (int q = 0; q < 4; q++) {
            int nb = hf * 4 + q;
            f32x4 a = {0.f, 0.f, 0.f, 0.f};
            #pragma unroll
            for (int ks = 0; ks < 4; ks++)
                a = mfma16(a2[ks], b2g[(nb * 4 + ks) * 64 + l], a);
            acc[q] = a;
        }
        int ch0 = lr * 8 + hf * 4;             // canonical channels (x1 side)
        int pos0 = hf * 64 + lr * 4;           // permuted msg position
        float4 bv = *reinterpret_cast<const float4*>(&fn2_b[ch0]);

        #pragma unroll
        for (int j = 0; j < 4; j++) {
            uint2 xp = *reinterpret_cast<const uint2*>(&x1[(size_t)cc4[j] * CC + ch0]);
            half2v x01 = __builtin_bit_cast(half2v, xp.x);
            half2v x23 = __builtin_bit_cast(half2v, xp.y);
            half2v p0, p1;
            p0[0] = (_Float16)((float)x01[0] * (acc[0][j] + bv.x));
            p0[1] = (_Float16)((float)x01[1] * (acc[1][j] + bv.y));
            p1[0] = (_Float16)((float)x23[0] * (acc[2][j] + bv.z));
            p1[1] = (_Float16)((float)x23[1] * (acc[3][j] + bv.w));
            uint2 st;
            st.x = __builtin_bit_cast(unsigned, p0);
            st.y = __builtin_bit_cast(unsigned, p1);
            *reinterpret_cast<uint2*>(&msg[(size_t)pp[j] * CC + pos0]) = st;
        }
    }
}

// ---------------------------------------------------------------------------
// Kernel B: CSR reduce (position-wise, layout-agnostic). Wave per node; msg
// rows for a node are CONSECUTIVE -> linear streaming. f32 accum, zero atomics.
// ---------------------------------------------------------------------------
__global__ __launch_bounds__(512, 8) void gather_reduce_kernel(
    const _Float16* __restrict__ msg, const int* __restrict__ rowptr,
    _Float16* __restrict__ aggH)
{
    int tid = threadIdx.x;
    int r = blockIdx.x * 8 + (tid >> 6);
    int l = tid & 63;
    int e0 = rowptr[r];
    int e1 = (r == NN - 1) ? NE : rowptr[r + 1];

    const unsigned* base = reinterpret_cast<const unsigned*>(msg) + l;
    float a0 = 0.f, a1 = 0.f;
    int i = e0;
    for (; i + 1 < e1; i += 2) {
        unsigned v0 = base[(size_t)i * 64];
        unsigned v1 = base[(size_t)(i + 1) * 64];
        half2v h0 = __builtin_bit_cast(half2v, v0);
        half2v h1 = __builtin_bit_cast(half2v, v1);
        a0 += (float)h0[0] + (float)h1[0];
        a1 += (float)h0[1] + (float)h1[1];
    }
    if (i < e1) {
        half2v h = __builtin_bit_cast(half2v, base[(size_t)i * 64]);
        a0 += (float)h[0];
        a1 += (float)h[1];
    }
    half2v o;
    o[0] = (_Float16)a0;
    o[1] = (_Float16)a1;
    reinterpret_cast<unsigned*>(aggH)[(size_t)r * 64 + l] = __builtin_bit_cast(unsigned, o);
}

// ---------------- fallback atomic edge kernel (remapped stage 2) ------------
__global__ __launch_bounds__(512, 8) void edge_kernel_atomic(
    const _Float16* __restrict__ x1, const int* __restrict__ eidx,
    const float* __restrict__ ea, const _Float16* __restrict__ frag_ws,
    const float* __restrict__ fn1_b, const float* __restrict__ fn2_b,
    float* __restrict__ agg)
{
    __shared__ __align__(16) unsigned char u_lds[EPB * CC * 2];
    __shared__ int rows_l[EPB];
    __shared__ int cols_l[EPB];

    int tid = threadIdx.x;
    size_t eBase = (size_t)blockIdx.x * EPB;

    if (tid < EPB) {
        rows_l[tid] = eidx[eBase + tid];
        cols_l[tid] = eidx[(size_t)NE + eBase + tid];
    }
    {
        const float2* eap = reinterpret_cast<const float2*>(ea + eBase * GG);
        for (int i = tid; i < EPB * 25; i += 512) {
            int e = i / 25, g2 = i - e * 25;
            float2 v = eap[i];
            int byte = e * 128 + ((g2 * 4) ^ ((e & 7) << 4));
            _Float16* p = reinterpret_cast<_Float16*>(u_lds + byte);
            p[0] = (_Float16)v.x;
            p[1] = (_Float16)v.y;
        }
        for (int i = tid; i < EPB * 14; i += 512) {
            int e = i / 14, g = (i - e * 14) + 50;
            int byte = e * 128 + ((g * 2) ^ ((e & 7) << 4));
            *reinterpret_cast<_Float16*>(u_lds + byte) = (_Float16)0.f;
        }
    }
    __syncthreads();

    int wv = tid >> 6, l = tid & 63;
    int lr = l & 15, lg = l >> 4;
    int erow = wv * 16;

    half8 a1[2];
    #pragma unroll
    for (int ks = 0; ks < 2; ks++) {
        int e = erow + lr;
        int byte = e * 128 + ((ks * 64 + lg * 16) ^ ((e & 7) << 4));
        a1[ks] = *reinterpret_cast<const half8*>(u_lds + byte);
    }
    __syncthreads();

    #pragma unroll
    for (int nb = 0; nb < 8; nb++) {
        half8 b10 = *reinterpret_cast<const half8*>(&frag_ws[((nb * 2 + 0) * 64 + l) * 8]);
        half8 b11 = *reinterpret_cast<const half8*>(&frag_ws[((nb * 2 + 1) * 64 + l) * 8]);
        f32x4 acc = {0.f, 0.f, 0.f, 0.f};
        acc = mfma16(a1[0], b10, acc);
        acc = mfma16(a1[1], b11, acc);
        float bv = fn1_b[nb * 16 + lr];
        int f = nb * 16 + lr;
        #pragma unroll
        for (int j = 0; j < 4; j++) {
            float z = acc[j] + bv;
            float t = __expf(-fabsf(z));
            float hz = fmaxf(z, 0.f) + __logf(1.f + t) - 0.69314718055994531f;
            int e = erow + lg * 4 + j;
            int byte = e * 256 + ((f * 2) ^ ((e & 7) << 4));
            *reinterpret_cast<_Float16*>(u_lds + byte) = (_Float16)hz;
        }
    }
    __syncthreads();

    half8 a2[4];
    #pragma unroll
    for (int ks = 0; ks < 4; ks++) {
        int e = erow + lr;
        int byte = e * 256 + ((ks * 64 + lg * 16) ^ ((e & 7) << 4));
        a2[ks] = *reinterpret_cast<const half8*>(u_lds + byte);
    }
    int rr[4], cc4[4];
    #pragma unroll
    for (int j = 0; j < 4; j++) {
        int e = erow + lg * 4 + j;
        rr[j] = rows_l[e];
        cc4[j] = cols_l[e];
    }
    const half8* b2g = reinterpret_cast<const half8*>(frag_ws + 8192);
    #pragma unroll
    for (int hf = 0; hf < 2; hf++) {
        f32x4 acc[4];
        #pragma unroll
        for (int q = 0; q < 4; q++) {
            int nb = hf * 4 + q;
            f32x4 a = {0.f, 0.f, 0.f, 0.f};
            #pragma unroll
            for (int ks = 0; ks < 4; ks++)
                a = mfma16(a2[ks], b2g[(nb * 4 + ks) * 64 + l], a);
            acc[q] = a;
        }
        int ch0 = lr * 8 + hf * 4;
        float4 bv = *reinterpret_cast<const float4*>(&fn2_b[ch0]);
        #pragma unroll
        for (int j = 0; j < 4; j++) {
            uint2 xp = *reinterpret_cast<const uint2*>(&x1[(size_t)cc4[j] * CC + ch0]);
            half2v x01 = __builtin_bit_cast(half2v, xp.x);
            half2v x23 = __builtin_bit_cast(half2v, xp.y);
            float* dst = &agg[(size_t)rr[j] * CC + ch0];
            atomicAdd(dst + 0, (float)x01[0] * (acc[0][j] + bv.x));
            atomicAdd(dst + 1, (float)x01[1] * (acc[1][j] + bv.y));
            atomicAdd(dst + 2, (float)x23[0] * (acc[2][j] + bv.z));
            atomicAdd(dst + 3, (float)x23[1] * (acc[3][j] + bv.w));
        }
    }
}

extern "C" void kernel_launch(void* const* d_in, const int* in_sizes, int n_in,
                              void* d_out, int out_size, void* d_ws, size_t ws_size,
                              hipStream_t stream) {
    const float* x      = (const float*)d_in[0];
    const int*   eidx   = (const int*)d_in[1];
    const float* ea     = (const float*)d_in[2];
    const float* lin1_w = (const float*)d_in[3];
    const float* lin1_b = (const float*)d_in[4];
    const float* lin2_w = (const float*)d_in[5];
    const float* lin2_b = (const float*)d_in[6];
    const float* fn1_w  = (const float*)d_in[7];
    const float* fn1_b  = (const float*)d_in[8];
    const float* fn2_w  = (const float*)d_in[9];
    const float* fn2_b  = (const float*)d_in[10];

    float* out = (float*)d_out;

    // ws layout (bytes)
    const size_t o_frag = 0;                                   // 48 KB used
    const size_t o_x1h  = 65536;                               // 25.6 MB
    const size_t o_msg  = o_x1h + (size_t)NN * CC * 2;         // 409.6 MB
    const size_t o_aggH = o_msg + (size_t)NE * CC * 2;         // 25.6 MB
    const size_t o_cnt  = o_aggH + (size_t)NN * CC * 2;        // 400 KB
    const size_t o_rp   = o_cnt + (size_t)NN * 4;              // 400 KB
    const size_t o_cur  = o_rp + (size_t)NN * 4;               // 400 KB
    const size_t o_bsum = o_cur + (size_t)NN * 4;              // 512 B
    const size_t req    = o_bsum + 512;

    _Float16* frag_ws = (_Float16*)((char*)d_ws + o_frag);
    _Float16* x1h     = (_Float16*)((char*)d_ws + o_x1h);

    pack_frags<<<1, 256, 0, stream>>>(fn1_w, fn2_w, frag_ws);

    if (ws_size >= req) {
        _Float16* msg  = (_Float16*)((char*)d_ws + o_msg);
        _Float16* aggH = (_Float16*)((char*)d_ws + o_aggH);
        int* cnt    = (int*)((char*)d_ws + o_cnt);
        int* rowptr = (int*)((char*)d_ws + o_rp);
        int* cursor = (int*)((char*)d_ws + o_cur);
        int* bsum   = (int*)((char*)d_ws + o_bsum);

        hipMemsetAsync(cnt, 0, (size_t)NN * 4, stream);
        // lin1 + fused histogram (atomics hide under MFMA)
        lin_kernel<float, _Float16, true, false><<<(NN + 63) / 64, 256, 0, stream>>>(
            x, lin1_w, lin1_b, x1h, NN, eidx, cnt);
        scanA<<<NSCB, 256, 0, stream>>>(cnt, rowptr, bsum, NN);
        scanB<<<1, 128, 0, stream>>>(bsum, NSCB);
        scanC<<<NSCB, 256, 0, stream>>>(rowptr, bsum, cursor, NN);

        msg_scatter_kernel<<<NE / EPB, 512, 0, stream>>>(x1h, eidx, ea, frag_ws,
                                                         fn1_b, fn2_b, cursor, msg);
        gather_reduce_kernel<<<NN / 8, 512, 0, stream>>>(msg, rowptr, aggH);
        // lin2 with permuted K to match msg/agg position layout
        lin_kernel<_Float16, float, false, true><<<(NN + 63) / 64, 256, 0, stream>>>(
            aggH, lin2_w, lin2_b, out, NN, nullptr, nullptr);
    } else {
        lin_kernel<float, _Float16, false, false><<<(NN + 63) / 64, 256, 0, stream>>>(
            x, lin1_w, lin1_b, x1h, NN, nullptr, nullptr);
        hipMemsetAsync(out, 0, (size_t)NN * CC * sizeof(float), stream);
        edge_kernel_atomic<<<NE / EPB, 512, 0, stream>>>(x1h, eidx, ea, frag_ws,
                                                         fn1_b, fn2_b, out);
        lin_kernel<float, float, false, false><<<(NN + 63) / 64, 256, 0, stream>>>(
            out, lin2_w, lin2_b, out, NN, nullptr, nullptr);
    }
}